// Round 5
// baseline (404.903 us; speedup 1.0000x reference)
//
#include <hip/hip_runtime.h>

typedef unsigned short ushort_t;
typedef __attribute__((ext_vector_type(8))) short short8;
typedef __attribute__((ext_vector_type(4))) float f32x4;

#define AS1 __attribute__((address_space(1)))
#define AS3 __attribute__((address_space(3)))

__device__ __forceinline__ ushort_t f2bf(float f) {
  unsigned int u = __builtin_bit_cast(unsigned int, f);
  u += 0x7fffu + ((u >> 16) & 1u);            // round-to-nearest-even
  return (ushort_t)(u >> 16);
}

// pack two floats to bf16x2 (round-half-up fallback; HW cvt_pk when available)
__device__ __forceinline__ unsigned int pack_bf2(float a, float b) {
  unsigned int ua = __builtin_bit_cast(unsigned int, a) + 0x8000u;
  unsigned int ub = __builtin_bit_cast(unsigned int, b) + 0x8000u;
  return (ua >> 16) | (ub & 0xffff0000u);
}

#if defined(__has_builtin)
#if __has_builtin(__builtin_amdgcn_cvt_pk_bf16_f32)
#define HAVE_CVT_PK_BF16 1
#endif
#if __has_builtin(__builtin_amdgcn_exp2f)
#define HAVE_EXP2 1
#endif
#endif

__device__ __forceinline__ unsigned int pack2(float a, float b) {
#ifdef HAVE_CVT_PK_BF16
  typedef __attribute__((ext_vector_type(2))) __bf16 bf2_t;
  bf2_t r = __builtin_amdgcn_cvt_pk_bf16_f32(a, b);
  return __builtin_bit_cast(unsigned int, r);
#else
  return pack_bf2(a, b);
#endif
}

__device__ __forceinline__ float fast_exp2(float x) {
#ifdef HAVE_EXP2
  return __builtin_amdgcn_exp2f(x);
#else
  return exp2f(x);
#endif
}

__device__ __forceinline__ void load_lds16(const ushort_t* g, ushort_t* l) {
  __builtin_amdgcn_global_load_lds((AS1 void*)g, (AS3 void*)l, 16, 0, 0);
}

#define MFMA16(a, b, c) __builtin_amdgcn_mfma_f32_16x16x32_bf16((a), (b), (c), 0, 0, 0)
#define BAR() __builtin_amdgcn_s_barrier()
#define SCHEDB() __builtin_amdgcn_sched_barrier(0)
// counted vmcnt wait (never 0 in main loops); double-expansion for macro args
#define WAITV_(N) asm volatile("s_waitcnt vmcnt(" #N ")" ::: "memory")
#define WAITV(N) WAITV_(N)

// ---------------- fused prep: hs convert (blocks 0..4095) + wqkv transpose
// (4096..4863) + wproj transpose (4864..5119). One launch, runs concurrently.
__global__ __launch_bounds__(256) void k_prep(const float* __restrict__ hs,
                                              ushort_t* __restrict__ hsb,
                                              const float* __restrict__ wqkv,
                                              ushort_t* __restrict__ wqkvT,
                                              const float* __restrict__ wproj,
                                              ushort_t* __restrict__ wprojT) {
  __shared__ ushort_t t[64 * 65];
  const int bid = blockIdx.x;
  if (bid < 4096) {  // ---- convert hs fp32 -> bf16, 8 elems/thread
    int i = bid * 256 + threadIdx.x;
    const float4* s4 = (const float4*)hs;
    float4 a = s4[(size_t)i * 2], b = s4[(size_t)i * 2 + 1];
    short8 o;
    o[0] = (short)f2bf(a.x); o[1] = (short)f2bf(a.y);
    o[2] = (short)f2bf(a.z); o[3] = (short)f2bf(a.w);
    o[4] = (short)f2bf(b.x); o[5] = (short)f2bf(b.y);
    o[6] = (short)f2bf(b.z); o[7] = (short)f2bf(b.w);
    *(short8*)(hsb + (size_t)i * 8) = o;
    return;
  }
  // ---- transpose fp32 [1024][C] -> bf16 [C][1024]
  const float* src;
  ushort_t* dst;
  int C, bx, by;
  if (bid < 4864) { int idx = bid - 4096; src = wqkv; dst = wqkvT; C = 3072;
                    bx = idx % 48; by = idx / 48; }
  else            { int idx = bid - 4864; src = wproj; dst = wprojT; C = 1024;
                    bx = idx & 15; by = idx >> 4; }
  const int R = 1024;
  const int x0 = bx * 64, y0 = by * 64;
  const int c = threadIdx.x & 63, r0 = threadIdx.x >> 6;
#pragma unroll
  for (int i = 0; i < 16; ++i) {
    int r = r0 + i * 4;
    t[c * 65 + r] = f2bf(src[(size_t)(y0 + r) * C + x0 + c]);
  }
  __syncthreads();
#pragma unroll
  for (int i = 0; i < 16; ++i) {
    int rr = r0 + i * 4;
    dst[(size_t)(x0 + rr) * R + y0 + c] = t[rr * 65 + c];
  }
}

// ---------------------------------------------------------------- qkv GEMM + RoPE
// A: hs bf16 [8192][1024], Bt: wqkv^T bf16 [3072][1024]
// 128x128 tile, 256 threads (4 waves: 2 on M x 2 on N, 64x64 each), BK=32.
// TRIPLE-buffered, prefetch depth 2, counted vmcnt (T4, never 0 in loop):
//   step kt: [BAR][issue L(kt+2) -> buf (kt+2)%3][ds_read+MFMA buf kt%3]
//            [WAITV(4): own L(kt+1) done (L(kt+2)'s 4 remain)]
//   -> at next BAR all waves' L(kt+1) landed (each waited own before barrier);
//   overwrite of buf (kt-1)%3 is after the BAR that follows step kt-1 compute.
// LDS 3x16KB = 48KB -> 3 blocks/CU (12 waves). Grid 1536 = 6/CU balanced.
// 64B-row swizzle: source chunk s^((r>>1)&3), reader chunk (quad^((row>>1)&3))&3.
// XCD swizzle: xcd=L&7, j=L>>3, by=xcd*8+j/24, bx=j%24 (24 N-tiles of one
// A-row-panel share one XCD; A panel 256KB, 8 panels = 2MB fits its L2).
// Q: RoPE'd AND pre-scaled by 0.125*log2(e). K: RoPE'd [B*H][L][D].
// V: transposed pi-space Vp[bh][d][lB + pi(lt)], pi(lt)=4*(lt&15)+(lt>>4).
__global__ __launch_bounds__(256, 3) void k_qkv_gemm_rope(
    const ushort_t* __restrict__ A, const ushort_t* __restrict__ Bt,
    const float* __restrict__ bias, const float* __restrict__ cosb,
    const float* __restrict__ sinb, ushort_t* __restrict__ Qb,
    ushort_t* __restrict__ Kb, ushort_t* __restrict__ Vp) {
  constexpr int K = 1024;
  __shared__ __align__(16) ushort_t As[3][4096];  // 3 x 128x32 bf16
  __shared__ __align__(16) ushort_t Bs[3][4096];
  const int tid = threadIdx.x, lane = tid & 63, wave = tid >> 6;
  const int quad = lane >> 4, ml = lane & 15;
  const int wm = wave & 1, wn = wave >> 1;
  const int L = blockIdx.x, xcd = L & 7, j = L >> 3;
  const int by = xcd * 8 + j / 24, bx = j % 24;
  const int m0 = by * 128, n0 = bx * 128;
  f32x4 acc[4][4] = {};

  // staging: A 512 chunks + B 512 chunks of 16B; 2+2 per thread per step
  const ushort_t* ag[2];
  const ushort_t* bg[2];
  ushort_t *alp[2], *blp[2];
#pragma unroll
  for (int i = 0; i < 2; ++i) {
    int cch = i * 256 + tid;
    int r = cch >> 2, s = cch & 3, gs = s ^ ((r >> 1) & 3);
    ag[i] = A + (size_t)(m0 + r) * K + gs * 8;
    bg[i] = Bt + (size_t)(n0 + r) * K + gs * 8;
    alp[i] = &As[0][0] + cch * 8;
    blp[i] = &Bs[0][0] + cch * 8;
  }

  // hoisted fragment offsets (ushort units, within one 4096-elem buffer)
  int afo[4], bfo[4];
#pragma unroll
  for (int mb = 0; mb < 4; ++mb) {
    int row = wm * 64 + mb * 16 + ml;
    afo[mb] = row * 32 + ((quad ^ ((row >> 1) & 3)) & 3) * 8;
  }
#pragma unroll
  for (int nb = 0; nb < 4; ++nb) {
    int row = wn * 64 + nb * 16 + ml;
    bfo[nb] = row * 32 + ((quad ^ ((row >> 1) & 3)) & 3) * 8;
  }

  // prologue: L(0)->buf0, L(1)->buf1, then wait own L(0) (4 newest = L(1) remain)
#pragma unroll
  for (int i = 0; i < 2; ++i) {
    load_lds16(ag[i], alp[i]); load_lds16(bg[i], blp[i]);
    ag[i] += 32; bg[i] += 32;
  }
#pragma unroll
  for (int i = 0; i < 2; ++i) {
    load_lds16(ag[i], alp[i] + 4096); load_lds16(bg[i], blp[i] + 4096);
    ag[i] += 32; bg[i] += 32;
  }
  WAITV(4);

#define GSTEP(BUF, NBUF, ISS, WN)                                             \
  {                                                                           \
    BAR();                                                                    \
    SCHEDB();                                                                 \
    if (ISS) {                                                                \
      load_lds16(ag[0], alp[0] + (NBUF) * 4096); ag[0] += 32;                 \
      load_lds16(ag[1], alp[1] + (NBUF) * 4096); ag[1] += 32;                 \
      load_lds16(bg[0], blp[0] + (NBUF) * 4096); bg[0] += 32;                 \
      load_lds16(bg[1], blp[1] + (NBUF) * 4096); bg[1] += 32;                 \
    }                                                                         \
    short8 af[4], bfr[4];                                                     \
    _Pragma("unroll") for (int mb = 0; mb < 4; ++mb)                          \
        af[mb] = *(const short8*)(&As[0][0] + (BUF) * 4096 + afo[mb]);        \
    _Pragma("unroll") for (int nb = 0; nb < 4; ++nb)                          \
        bfr[nb] = *(const short8*)(&Bs[0][0] + (BUF) * 4096 + bfo[nb]);       \
    __builtin_amdgcn_s_setprio(1);                                            \
    _Pragma("unroll") for (int mb = 0; mb < 4; ++mb)                          \
      _Pragma("unroll") for (int nb = 0; nb < 4; ++nb)                        \
          acc[mb][nb] = MFMA16(af[mb], bfr[nb], acc[mb][nb]);                 \
    __builtin_amdgcn_s_setprio(0);                                            \
    WAITV(WN);                                                                \
  }

#pragma unroll 1
  for (int t3 = 0; t3 < 10; ++t3) {  // steps 0..29 (issue L2..L31)
    GSTEP(0, 2, 1, 4)
    GSTEP(1, 0, 1, 4)
    GSTEP(2, 1, 1, 4)
  }
  GSTEP(0, 0, 0, 0)  // step 30: drain L(31)
  GSTEP(1, 0, 0, 0)  // step 31
#undef GSTEP

  // epilogue
  const int ncol0 = n0 + wn * 64;
  const int sec = ncol0 >> 10;  // 0=q 1=k 2=v
  const int h = (ncol0 & 1023) >> 6;
  if (sec < 2) {
    ushort_t* dst = (sec == 0) ? Qb : Kb;
    const float qs = (sec == 0) ? 0.18033688011112042f : 1.0f;  // log2(e)/8 into Q
#pragma unroll
    for (int mb = 0; mb < 4; ++mb) {
#pragma unroll
      for (int rg = 0; rg < 4; ++rg) {
        const int m = m0 + wm * 64 + mb * 16 + quad * 4 + rg;
        const int b = m >> 10, l = m & 1023;
        const size_t ob = ((size_t)(b * 16 + h) * 1024 + l) * 64;
#pragma unroll
        for (int nb = 0; nb < 2; ++nb) {
          const int d = nb * 16 + ml;
          float x1 = acc[mb][nb][rg] + bias[ncol0 + d];
          float x2 = acc[mb][nb + 2][rg] + bias[ncol0 + d + 32];
          float cv = cosb[(size_t)m * 64 + d] * qs;
          float sv = sinb[(size_t)m * 64 + d] * qs;
          dst[ob + d] = f2bf(x1 * cv - x2 * sv);
          dst[ob + d + 32] = f2bf(x2 * cv + x1 * sv);
        }
      }
    }
  } else {
    // V^T pi-space: addr = [bh][d][lB + 16*quad + 4*rg + mb], mb packs into b64
    const int mrow = m0 + wm * 64;
    const int b = mrow >> 10, lB = mrow & 1023;
    ushort_t* vb = Vp + ((size_t)(b * 16 + h)) * 65536 + lB;
#pragma unroll
    for (int rg = 0; rg < 4; ++rg) {
#pragma unroll
      for (int nb = 0; nb < 4; ++nb) {
        const int d = nb * 16 + ml;
        const float bs = bias[ncol0 + d];
        uint2 w;
        w.x = pack_bf2(acc[0][nb][rg] + bs, acc[1][nb][rg] + bs);
        w.y = pack_bf2(acc[2][nb][rg] + bs, acc[3][nb][rg] + bs);
        *(uint2*)(vb + (size_t)d * 1024 + 16 * quad + 4 * rg) = w;
      }
    }
  }
}

// ---------------------------------------------------------------- flash attention
// Q(prescaled)/K bf16 [B*H][L][D]; Vp bf16 [B*H][D][L] (pi-space l);
// out: attn bf16 [T][H*D]. 512 threads (8 waves x 32 q = 256 q/block).
// Q: direct global->register fragment loads (no LDS staging, no barriers).
// K TRIPLE-buffered (2-step prefetch), V DOUBLE-buffered (1.5-step prefetch),
// counted vmcnt, two barriers per step, no drains:
//   step kt: [BAR: K(kt) globally done - each wave waited own at kt-1's WAITV]
//            [issue K(kt+2)->Ks[(kt+2)%3], V(kt+1)->Vts[(kt+1)%2]]
//            [QK from Ks[kt%3]] [softmax -> P (wave-private LDS)]
//            [WAITV(2): own V(kt)+K(kt+1) done; K(kt+2),V(kt+1) remain]
//            [BAR: V(kt) globally done] [PV from Vts[kt%2]]
// Overwrites are protected by the top BAR (follows all waves' prior compute).
// LDS: P 32KB + K 24KB + V 16KB = 72KB -> 2 blocks/CU (16 waves). Grid 512 =
// exactly 2/CU, zero tail. bh = id&127 -> qt-blocks of one bh on one XCD.
__global__ __launch_bounds__(512, 4) void k_attn(const ushort_t* __restrict__ Qb,
                                                 const ushort_t* __restrict__ Kb,
                                                 const ushort_t* __restrict__ Vp,
                                                 ushort_t* __restrict__ Ob) {
  __shared__ __align__(16) ushort_t Ps[16384];     // 32KB: P 8x[32][64] swizzled
  __shared__ __align__(16) ushort_t Ks[3][4096];   // K tiles, triple-buffered
  __shared__ __align__(16) ushort_t Vts[2][4096];  // V^T tiles, double-buffered
  const int tid = threadIdx.x, lane = tid & 63, wave = tid >> 6;
  const int quad = lane >> 4, ml = lane & 15;
  const int bh = blockIdx.x & 127, qt = blockIdx.x >> 7;  // 512 blocks, qt 0..3
  const int q0 = qt * 256;
  const size_t base = (size_t)bh * 65536;

  // Q fragments direct to registers (A-operand: row=ml, cols ks*32+quad*8)
  short8 qf[2][2];
#pragma unroll
  for (int mb = 0; mb < 2; ++mb)
#pragma unroll
    for (int ks = 0; ks < 2; ++ks)
      qf[mb][ks] = *(const short8*)(Qb + base +
          (size_t)(q0 + wave * 32 + mb * 16 + ml) * 64 + ks * 32 + quad * 8);

  // staging pointers: 512 threads, 512 chunks/tile -> 1 chunk per thread
  const ushort_t* kg;
  const ushort_t* vg;
  ushort_t *kl, *vl;
  {
    int r = tid >> 3, gs = (tid & 7) ^ (r & 7);
    kg = Kb + base + (size_t)r * 64 + gs * 8;
    kl = &Ks[0][0] + tid * 8;
    vg = Vp + base + (size_t)r * 1024 + gs * 8;
    vl = &Vts[0][0] + tid * 8;
  }
  // prologue: K0 -> Ks[0], V0 -> Vts[0], K1 -> Ks[1]
  load_lds16(kg, kl); kg += 4096;
  load_lds16(vg, vl); vg += 64;
  load_lds16(kg, kl + 4096); kg += 4096;

  ushort_t* Pw = Ps + wave * 2048;  // per-wave P [32][64] XOR-swizzled

  // hoisted LDS fragment pointers (buffer offset added as compile-time const)
  const ushort_t* kfp[4][2];
  const ushort_t* vfp[4][2];
#pragma unroll
  for (int nb = 0; nb < 4; ++nb)
#pragma unroll
    for (int ks = 0; ks < 2; ++ks) {
      int row = nb * 16 + ml;
      int gs = (ks * 4 + quad) ^ (row & 7);
      kfp[nb][ks] = &Ks[0][0] + row * 64 + gs * 8;
      vfp[nb][ks] = &Vts[0][0] + row * 64 + gs * 8;
    }
  // P read ptrs: row=mb*16+ml, 16B group (ks*4+quad)^(row&7)
  const ushort_t* pfp[2][2];
#pragma unroll
  for (int mb = 0; mb < 2; ++mb)
#pragma unroll
    for (int ks = 0; ks < 2; ++ks) {
      int row = mb * 16 + ml;
      int gs = ((ks * 4 + quad) ^ row) & 7;
      pfp[mb][ks] = Pw + row * 64 + gs * 8;
    }
  // P write ptrs: row=mb*16+quad*4+rg, 8B at group (ml>>1)^(row&7), sub (ml&1)*4
  ushort_t* pwp[2][4];
#pragma unroll
  for (int mb = 0; mb < 2; ++mb)
#pragma unroll
    for (int rg = 0; rg < 4; ++rg) {
      int row = mb * 16 + quad * 4 + rg;
      int g = ((ml >> 1) ^ row) & 7;
      pwp[mb][rg] = Pw + row * 64 + g * 8 + (ml & 1) * 4;
    }

  f32x4 Oacc[2][4] = {};
  float lsum[2][4] = {};

  WAITV(2);  // own K0 done (V0, K1 remain; Q loads are older -> also done)

#define ATTN_STEP(KB, NKB, VB, ISSK, ISSV, WN)                                \
  {                                                                           \
    BAR();                                                                    \
    SCHEDB();                                                                 \
    if (ISSK) { load_lds16(kg, kl + (NKB) * 4096); kg += 4096; }              \
    if (ISSV) { load_lds16(vg, vl + ((VB) ^ 1) * 4096); vg += 64; }           \
    f32x4 Sacc[2][4] = {};                                                    \
    __builtin_amdgcn_s_setprio(1);                                            \
    _Pragma("unroll") for (int nb = 0; nb < 4; ++nb)                          \
      _Pragma("unroll") for (int ks = 0; ks < 2; ++ks) {                      \
        short8 kf = *(const short8*)(kfp[nb][ks] + (KB) * 4096);              \
        Sacc[0][nb] = MFMA16(qf[0][ks], kf, Sacc[0][nb]);                     \
        Sacc[1][nb] = MFMA16(qf[1][ks], kf, Sacc[1][nb]);                     \
      }                                                                       \
    __builtin_amdgcn_s_setprio(0);                                            \
    _Pragma("unroll") for (int mb = 0; mb < 2; ++mb) {                        \
      _Pragma("unroll") for (int rg = 0; rg < 4; ++rg) {                      \
        float p0 = fast_exp2(Sacc[mb][0][rg]);                                \
        float p1 = fast_exp2(Sacc[mb][1][rg]);                                \
        float p2 = fast_exp2(Sacc[mb][2][rg]);                                \
        float p3 = fast_exp2(Sacc[mb][3][rg]);                                \
        lsum[mb][rg] += (p0 + p1) + (p2 + p3);                                \
        uint2 w;                                                              \
        w.x = pack2(p0, p1);                                                  \
        w.y = pack2(p2, p3);                                                  \
        *(uint2*)pwp[mb][rg] = w;                                             \
      }                                                                       \
    }                                                                         \
    WAITV(WN);                                                                \
    BAR();                                                                    \
    SCHEDB();                                                                 \
    __builtin_amdgcn_s_setprio(1);                                            \
    _Pragma("unroll") for (int ks = 0; ks < 2; ++ks) {                        \
      short8 pf0 = *(const short8*)pfp[0][ks];                                \
      short8 pf1 = *(const short8*)pfp[1][ks];                                \
      _Pragma("unroll") for (int nb = 0; nb < 4; ++nb) {                      \
        short8 vf = *(const short8*)(vfp[nb][ks] + (VB) * 4096);              \
        Oacc[0][nb] = MFMA16(pf0, vf, Oacc[0][nb]);                           \
        Oacc[1][nb] = MFMA16(pf1, vf, Oacc[1][nb]);                           \
      }                                                                       \
    }                                                                         \
    __builtin_amdgcn_s_setprio(0);                                            \
  }

  // kt = 0..15; KB=kt%3, NKB=(kt+2)%3, VB=kt%2.
  // Steps 0..13 issue K(kt+2); steps 0..14 issue V(kt+1).
#pragma unroll 1
  for (int t6 = 0; t6 < 2; ++t6) {  // kt 0..5, 6..11
    ATTN_STEP(0, 2, 0, 1, 1, 2)
    ATTN_STEP(1, 0, 1, 1, 1, 2)
    ATTN_STEP(2, 1, 0, 1, 1, 2)
    ATTN_STEP(0, 2, 1, 1, 1, 2)
    ATTN_STEP(1, 0, 0, 1, 1, 2)
    ATTN_STEP(2, 1, 1, 1, 1, 2)
  }
  ATTN_STEP(0, 2, 0, 1, 1, 2)  // kt 12: K14, V13
  ATTN_STEP(1, 0, 1, 1, 1, 2)  // kt 13: K15, V14
  ATTN_STEP(2, 0, 0, 0, 1, 1)  // kt 14: V15 only; wait leaves V15
  ATTN_STEP(0, 0, 1, 0, 0, 0)  // kt 15: drain V15
#undef ATTN_STEP

  // epilogue: reduce lsum across the 16 lanes of each quad, normalize, store
  const int b = bh >> 4, h = bh & 15;
#pragma unroll
  for (int mb = 0; mb < 2; ++mb) {
#pragma unroll
    for (int rg = 0; rg < 4; ++rg) {
      float l = lsum[mb][rg];
      l += __shfl_xor(l, 1);
      l += __shfl_xor(l, 2);
      l += __shfl_xor(l, 4);
      l += __shfl_xor(l, 8);
      float inv = 1.f / l;
      int q = q0 + wave * 32 + mb * 16 + quad * 4 + rg;
      size_t ob = ((size_t)(b * 1024 + q)) * 1024 + h * 64;
#pragma unroll
      for (int nb = 0; nb < 4; ++nb)
        Ob[ob + nb * 16 + ml] = f2bf(Oacc[mb][nb][rg] * inv);
    }
  }
}

// ---------------------------------------------------------------- proj GEMM
// A: attn bf16 [8192][1024], Bt: wproj^T bf16 [1024][1024].
// Same triple-buffered BK=32 pipeline as k_qkv_gemm_rope (128x128, 256 thr).
// Grid 512, XCD-swizzled: by=xcd*8+(j>>3), bx=j&7.
__global__ __launch_bounds__(256, 3) void k_proj_gemm(const ushort_t* __restrict__ A,
                                                      const ushort_t* __restrict__ Bt,
                                                      const float* __restrict__ bias,
                                                      float* __restrict__ out) {
  constexpr int K = 1024;
  __shared__ __align__(16) ushort_t As[3][4096];
  __shared__ __align__(16) ushort_t Bs[3][4096];
  const int tid = threadIdx.x, lane = tid & 63, wave = tid >> 6;
  const int quad = lane >> 4, ml = lane & 15;
  const int wm = wave & 1, wn = wave >> 1;
  const int L = blockIdx.x, xcd = L & 7, j = L >> 3;
  const int by = xcd * 8 + (j >> 3), bx = j & 7;
  const int m0 = by * 128, n0 = bx * 128;
  f32x4 acc[4][4] = {};

  const ushort_t* ag[2];
  const ushort_t* bg[2];
  ushort_t *alp[2], *blp[2];
#pragma unroll
  for (int i = 0; i < 2; ++i) {
    int cch = i * 256 + tid;
    int r = cch >> 2, s = cch & 3, gs = s ^ ((r >> 1) & 3);
    ag[i] = A + (size_t)(m0 + r) * K + gs * 8;
    bg[i] = Bt + (size_t)(n0 + r) * K + gs * 8;
    alp[i] = &As[0][0] + cch * 8;
    blp[i] = &Bs[0][0] + cch * 8;
  }
  int afo[4], bfo[4];
#pragma unroll
  for (int mb = 0; mb < 4; ++mb) {
    int row = wm * 64 + mb * 16 + ml;
    afo[mb] = row * 32 + ((quad ^ ((row >> 1) & 3)) & 3) * 8;
  }
#pragma unroll
  for (int nb = 0; nb < 4; ++nb) {
    int row = wn * 64 + nb * 16 + ml;
    bfo[nb] = row * 32 + ((quad ^ ((row >> 1) & 3)) & 3) * 8;
  }

#pragma unroll
  for (int i = 0; i < 2; ++i) {
    load_lds16(ag[i], alp[i]); load_lds16(bg[i], blp[i]);
    ag[i] += 32; bg[i] += 32;
  }
#pragma unroll
  for (int i = 0; i < 2; ++i) {
    load_lds16(ag[i], alp[i] + 4096); load_lds16(bg[i], blp[i] + 4096);
    ag[i] += 32; bg[i] += 32;
  }
  WAITV(4);

#define GSTEP(BUF, NBUF, ISS, WN)                                             \
  {                                                                           \
    BAR();                                                                    \
    SCHEDB();                                                                 \
    if (ISS) {                                                                \
      load_lds16(ag[0], alp[0] + (NBUF) * 4096); ag[0] += 32;                 \
      load_lds16(ag[1], alp[1] + (NBUF) * 4096); ag[1] += 32;                 \
      load_lds16(bg[0], blp[0] + (NBUF) * 4096); bg[0] += 32;                 \
      load_lds16(bg[1], blp[1] + (NBUF) * 4096); bg[1] += 32;                 \
    }                                                                         \
    short8 af[4], bfr[4];                                                     \
    _Pragma("unroll") for (int mb = 0; mb < 4; ++mb)                          \
        af[mb] = *(const short8*)(&As[0][0] + (BUF) * 4096 + afo[mb]);        \
    _Pragma("unroll") for (int nb = 0; nb < 4; ++nb)                          \
        bfr[nb] = *(const short8*)(&Bs[0][0] + (BUF) * 4096 + bfo[nb]);       \
    __builtin_amdgcn_s_setprio(1);                                            \
    _Pragma("unroll") for (int mb = 0; mb < 4; ++mb)                          \
      _Pragma("unroll") for (int nb = 0; nb < 4; ++nb)                        \
          acc[mb][nb] = MFMA16(af[mb], bfr[nb], acc[mb][nb]);                 \
    __builtin_amdgcn_s_setprio(0);                                            \
    WAITV(WN);                                                                \
  }

#pragma unroll 1
  for (int t3 = 0; t3 < 10; ++t3) {
    GSTEP(0, 2, 1, 4)
    GSTEP(1, 0, 1, 4)
    GSTEP(2, 1, 1, 4)
  }
  GSTEP(0, 0, 0, 0)
  GSTEP(1, 0, 0, 0)
#undef GSTEP

#pragma unroll
  for (int mb = 0; mb < 4; ++mb) {
#pragma unroll
    for (int rg = 0; rg < 4; ++rg) {
      const int m = m0 + wm * 64 + mb * 16 + quad * 4 + rg;
#pragma unroll
      for (int nb = 0; nb < 4; ++nb) {
        const int n = n0 + wn * 64 + nb * 16 + ml;
        out[(size_t)m * 1024 + n] = acc[mb][nb][rg] + bias[n];
      }
    }
  }
}

// ---------------------------------------------------------------- launch
extern "C" void kernel_launch(void* const* d_in, const int* in_sizes, int n_in,
                              void* d_out, int out_size, void* d_ws, size_t ws_size,
                              hipStream_t stream) {
  const float* hs = (const float*)d_in[0];
  const float* cosb = (const float*)d_in[1];
  const float* sinb = (const float*)d_in[2];
  const float* wqkv = (const float*)d_in[3];
  const float* bqkv = (const float*)d_in[4];
  const float* wproj = (const float*)d_in[5];
  const float* bproj = (const float*)d_in[6];
  float* out = (float*)d_out;

  char* ws = (char*)d_ws;
  ushort_t* hsb = (ushort_t*)(ws);
  ushort_t* wqkvT = (ushort_t*)(ws + (16u << 20));
  ushort_t* wprojT = (ushort_t*)(ws + (22u << 20));
  ushort_t* Qb = (ushort_t*)(ws + (24u << 20));
  ushort_t* Kb = (ushort_t*)(ws + (40u << 20));
  ushort_t* Vp = (ushort_t*)(ws + (56u << 20));
  ushort_t* attnb = hsb;  // hs consumed by qkv GEMM before attention writes

  k_prep<<<5120, 256, 0, stream>>>(hs, hsb, wqkv, wqkvT, wproj, wprojT);
  k_qkv_gemm_rope<<<1536, 256, 0, stream>>>(hsb, wqkvT, bqkv, cosb, sinb,
                                            Qb, Kb, Vp);
  k_attn<<<512, 512, 0, stream>>>(Qb, Kb, Vp, attnb);
  k_proj_gemm<<<512, 256, 0, stream>>>(attnb, wprojT, bproj, out);
}

// Round 6
// 261.805 us; speedup vs baseline: 1.5466x; 1.5466x over previous
//
#include <hip/hip_runtime.h>

typedef unsigned short ushort_t;
typedef __attribute__((ext_vector_type(8))) short short8;
typedef __attribute__((ext_vector_type(4))) float f32x4;

#define AS1 __attribute__((address_space(1)))
#define AS3 __attribute__((address_space(3)))

__device__ __forceinline__ ushort_t f2bf(float f) {
  unsigned int u = __builtin_bit_cast(unsigned int, f);
  u += 0x7fffu + ((u >> 16) & 1u);            // round-to-nearest-even
  return (ushort_t)(u >> 16);
}

// pack two floats to bf16x2 (round-half-up fallback; HW cvt_pk when available)
__device__ __forceinline__ unsigned int pack_bf2(float a, float b) {
  unsigned int ua = __builtin_bit_cast(unsigned int, a) + 0x8000u;
  unsigned int ub = __builtin_bit_cast(unsigned int, b) + 0x8000u;
  return (ua >> 16) | (ub & 0xffff0000u);
}

#if defined(__has_builtin)
#if __has_builtin(__builtin_amdgcn_cvt_pk_bf16_f32)
#define HAVE_CVT_PK_BF16 1
#endif
#if __has_builtin(__builtin_amdgcn_exp2f)
#define HAVE_EXP2 1
#endif
#endif

__device__ __forceinline__ unsigned int pack2(float a, float b) {
#ifdef HAVE_CVT_PK_BF16
  typedef __attribute__((ext_vector_type(2))) __bf16 bf2_t;
  bf2_t r = __builtin_amdgcn_cvt_pk_bf16_f32(a, b);
  return __builtin_bit_cast(unsigned int, r);
#else
  return pack_bf2(a, b);
#endif
}

__device__ __forceinline__ float fast_exp2(float x) {
#ifdef HAVE_EXP2
  return __builtin_amdgcn_exp2f(x);
#else
  return exp2f(x);
#endif
}

__device__ __forceinline__ void load_lds16(const ushort_t* g, ushort_t* l) {
  __builtin_amdgcn_global_load_lds((AS1 void*)g, (AS3 void*)l, 16, 0, 0);
}

#define MFMA16(a, b, c) __builtin_amdgcn_mfma_f32_16x16x32_bf16((a), (b), (c), 0, 0, 0)

// ---------------- fused prep: hs convert (blocks 0..4095) + wqkv transpose
// (4096..4863) + wproj transpose (4864..5119). One launch, runs concurrently.
__global__ __launch_bounds__(256) void k_prep(const float* __restrict__ hs,
                                              ushort_t* __restrict__ hsb,
                                              const float* __restrict__ wqkv,
                                              ushort_t* __restrict__ wqkvT,
                                              const float* __restrict__ wproj,
                                              ushort_t* __restrict__ wprojT) {
  __shared__ ushort_t t[64 * 65];
  const int bid = blockIdx.x;
  if (bid < 4096) {  // ---- convert hs fp32 -> bf16, 8 elems/thread
    int i = bid * 256 + threadIdx.x;
    const float4* s4 = (const float4*)hs;
    float4 a = s4[(size_t)i * 2], b = s4[(size_t)i * 2 + 1];
    short8 o;
    o[0] = (short)f2bf(a.x); o[1] = (short)f2bf(a.y);
    o[2] = (short)f2bf(a.z); o[3] = (short)f2bf(a.w);
    o[4] = (short)f2bf(b.x); o[5] = (short)f2bf(b.y);
    o[6] = (short)f2bf(b.z); o[7] = (short)f2bf(b.w);
    *(short8*)(hsb + (size_t)i * 8) = o;
    return;
  }
  // ---- transpose fp32 [1024][C] -> bf16 [C][1024]
  const float* src;
  ushort_t* dst;
  int C, bx, by;
  if (bid < 4864) { int idx = bid - 4096; src = wqkv; dst = wqkvT; C = 3072;
                    bx = idx % 48; by = idx / 48; }
  else            { int idx = bid - 4864; src = wproj; dst = wprojT; C = 1024;
                    bx = idx & 15; by = idx >> 4; }
  const int R = 1024;
  const int x0 = bx * 64, y0 = by * 64;
  const int c = threadIdx.x & 63, r0 = threadIdx.x >> 6;
#pragma unroll
  for (int i = 0; i < 16; ++i) {
    int r = r0 + i * 4;
    t[c * 65 + r] = f2bf(src[(size_t)(y0 + r) * C + x0 + c]);
  }
  __syncthreads();
#pragma unroll
  for (int i = 0; i < 16; ++i) {
    int rr = r0 + i * 4;
    dst[(size_t)(x0 + rr) * R + y0 + c] = t[rr * 65 + c];
  }
}

// ---------------------------------------------------------------- qkv GEMM + RoPE
// A: hs bf16 [8192][1024], Bt: wqkv^T bf16 [3072][1024]
// m97 configuration: 128x128 tile, BK=64, 256 threads (4 waves: 2M x 2N,
// 64x64 each), single-buffered drain structure (measured-best simple form;
// implicit wave-level overlap via 4 resident blocks/CU does the pipelining).
// LDS 32KB (As 16K + Bs 16K) -> 5 blocks/CU LDS-cap, ~4 resident w/ VGPR.
// Grid 1536, XCD-swizzled: xcd=L&7, j=L>>3, by=xcd*8+j/24, bx=j%24 -> the 24
// N-tiles sharing one A-row-panel co-locate on one XCD.
// Q: RoPE'd AND pre-scaled by 0.125*log2(e) (attn computes exp2(S) directly).
// K: RoPE'd, [B*H][L][D]. V: transposed pi-space Vp[bh][d][lB + pi(lt)],
// pi(lt)=4*(lt&15)+(lt>>4) -> mb is the stride-1 axis -> packed b64 stores.
__global__ __launch_bounds__(256) void k_qkv_gemm_rope(
    const ushort_t* __restrict__ A, const ushort_t* __restrict__ Bt,
    const float* __restrict__ bias, const float* __restrict__ cosb,
    const float* __restrict__ sinb, ushort_t* __restrict__ Qb,
    ushort_t* __restrict__ Kb, ushort_t* __restrict__ Vp) {
  constexpr int K = 1024;
  __shared__ __align__(16) ushort_t As[128 * 64];
  __shared__ __align__(16) ushort_t Bs[128 * 64];
  const int tid = threadIdx.x, lane = tid & 63, wave = tid >> 6;
  const int quad = lane >> 4, ml = lane & 15;
  const int wm = wave & 1, wn = wave >> 1;  // 2 waves on M, 2 on N
  const int L = blockIdx.x, xcd = L & 7, j = L >> 3;
  const int by = xcd * 8 + j / 24, bx = j % 24;   // XCD-local A reuse
  const int m0 = by * 128, n0 = bx * 128;
  f32x4 acc[4][4] = {};

  for (int kt = 0; kt < K / 64; ++kt) {
    __syncthreads();
    {
      const int kk0 = kt * 64;
#pragma unroll
      for (int i = 0; i < 4; ++i) {  // A-tile 128x64: 1024 chunks of 16B
        int cch = i * 256 + tid;
        int r = cch >> 3, s = cch & 7, gs = s ^ (r & 7);
        load_lds16(A + (size_t)(m0 + r) * K + kk0 + gs * 8, As + cch * 8);
      }
#pragma unroll
      for (int i = 0; i < 4; ++i) {  // B-tile 128x64
        int cch = i * 256 + tid;
        int r = cch >> 3, s = cch & 7, gs = s ^ (r & 7);
        load_lds16(Bt + (size_t)(n0 + r) * K + kk0 + gs * 8, Bs + cch * 8);
      }
    }
    __syncthreads();
#pragma unroll
    for (int ks = 0; ks < 2; ++ks) {
      short8 af[4], bfr[4];
#pragma unroll
      for (int mb = 0; mb < 4; ++mb) {
        int row = wm * 64 + mb * 16 + ml;
        int gs = (ks * 4 + quad) ^ (row & 7);
        af[mb] = *(const short8*)(As + row * 64 + gs * 8);
      }
#pragma unroll
      for (int nb = 0; nb < 4; ++nb) {
        int row = wn * 64 + nb * 16 + ml;
        int gs = (ks * 4 + quad) ^ (row & 7);
        bfr[nb] = *(const short8*)(Bs + row * 64 + gs * 8);
      }
#pragma unroll
      for (int mb = 0; mb < 4; ++mb)
#pragma unroll
        for (int nb = 0; nb < 4; ++nb)
          acc[mb][nb] = MFMA16(af[mb], bfr[nb], acc[mb][nb]);
    }
  }

  // epilogue (per-wave sub-tile is 64x64, identical logic to measured r1)
  const int ncol0 = n0 + wn * 64;
  const int sec = ncol0 >> 10;  // 0=q 1=k 2=v
  const int h = (ncol0 & 1023) >> 6;
  if (sec < 2) {
    ushort_t* dst = (sec == 0) ? Qb : Kb;
    const float qs = (sec == 0) ? 0.18033688011112042f : 1.0f;  // log2(e)/8 into Q
#pragma unroll
    for (int mb = 0; mb < 4; ++mb) {
#pragma unroll
      for (int rg = 0; rg < 4; ++rg) {
        const int m = m0 + wm * 64 + mb * 16 + quad * 4 + rg;
        const int b = m >> 10, l = m & 1023;
        const size_t ob = ((size_t)(b * 16 + h) * 1024 + l) * 64;
#pragma unroll
        for (int nb = 0; nb < 2; ++nb) {
          const int d = nb * 16 + ml;
          float x1 = acc[mb][nb][rg] + bias[ncol0 + d];
          float x2 = acc[mb][nb + 2][rg] + bias[ncol0 + d + 32];
          float cv = cosb[(size_t)m * 64 + d] * qs;
          float sv = sinb[(size_t)m * 64 + d] * qs;
          dst[ob + d] = f2bf(x1 * cv - x2 * sv);
          dst[ob + d + 32] = f2bf(x2 * cv + x1 * sv);
        }
      }
    }
  } else {
    // V^T pi-space: addr = [bh][d][lB + 16*quad + 4*rg + mb], mb packs into b64
    const int mrow = m0 + wm * 64;
    const int b = mrow >> 10, lB = mrow & 1023;
    ushort_t* vb = Vp + ((size_t)(b * 16 + h)) * 65536 + lB;
#pragma unroll
    for (int rg = 0; rg < 4; ++rg) {
#pragma unroll
      for (int nb = 0; nb < 4; ++nb) {
        const int d = nb * 16 + ml;
        const float bs = bias[ncol0 + d];
        uint2 w;
        w.x = pack_bf2(acc[0][nb][rg] + bs, acc[1][nb][rg] + bs);
        w.y = pack_bf2(acc[2][nb][rg] + bs, acc[3][nb][rg] + bs);
        *(uint2*)(vb + (size_t)d * 1024 + 16 * quad + 4 * rg) = w;
      }
    }
  }
}

// ---------------------------------------------------------------- flash attention
// (round-2-fix version, pass-verified in the round-3 bench)
// Q(prescaled)/K bf16 [B*H][L][D]; Vp bf16 [B*H][D][L] (pi-space l);
// out: attn bf16 [T][H*D]. 512 THREADS (8 waves x 32 q = 256 q/block).
// K AND V double-buffered, ONE barrier per kt-step:
//   at step kt: issue K/V[kt+1] -> buf^1; QK from Kbuf[cur] (resident since
//   prev barrier); softmax -> P (wave-private LDS: wave w's Q-frag reads and
//   P region are both exactly ushorts [2048w, 2048w+2048)); PV from Vbuf[cur];
//   __syncthreads (drains vmcnt -> kt+1 resident; buf[cur] reusable).
// LDS 32K(Q/P) + 16K(K dbuf) + 16K(V dbuf) = 64KB -> 2 blocks/CU; grid 512 =
// exactly 2/CU, zero tail. K/V L2 traffic halves (4 qt-blocks per bh).
// bh = id&127: the 4 qt-blocks of one bh differ by 128 ≡ 0 mod 8 -> same XCD.
__global__ __launch_bounds__(512, 4) void k_attn(const ushort_t* __restrict__ Qb,
                                                 const ushort_t* __restrict__ Kb,
                                                 const ushort_t* __restrict__ Vp,
                                                 ushort_t* __restrict__ Ob) {
  __shared__ __align__(16) ushort_t QP[16384];     // 32KB: Q 256x64, then P 8x[32][64]
  __shared__ __align__(16) ushort_t Ks[2][4096];   // K tiles, double-buffered
  __shared__ __align__(16) ushort_t Vts[2][4096];  // V^T tiles, double-buffered
  const int tid = threadIdx.x, lane = tid & 63, wave = tid >> 6;
  const int quad = lane >> 4, ml = lane & 15;
  const int bh = blockIdx.x & 127, qt = blockIdx.x >> 7;  // 512 blocks, qt 0..3
  const int q0 = qt * 256;
  const size_t base = (size_t)bh * 65536;

#pragma unroll
  for (int i = 0; i < 4; ++i) {  // stage Q 256x64 once (32KB, 2048 chunks)
    int cch = i * 512 + tid;
    int r = cch >> 3, s = cch & 7, gs = s ^ (r & 7);
    load_lds16(Qb + base + (size_t)(q0 + r) * 64 + gs * 8, QP + cch * 8);
  }

  // ---- staging pointers: 512 threads, 512 chunks/tile -> 1 chunk per thread
  const ushort_t* kg;
  const ushort_t* vg;
  ushort_t *kl, *vl;
  {
    int cch = tid;
    int r = cch >> 3, gs = (cch & 7) ^ (r & 7);
    kg = Kb + base + (size_t)r * 64 + gs * 8;
    kl = Ks[0] + cch * 8;
    vg = Vp + base + (size_t)r * 1024 + gs * 8;
    vl = Vts[0] + cch * 8;
  }
  // prologue: K0/V0 into buf 0 (issued with Q; one drain for all)
  load_lds16(kg, kl); kg += 4096;  // next 64 key rows
  load_lds16(vg, vl); vg += 64;    // next 64 pi-cols
  __syncthreads();  // Q + K0 + V0 resident

  short8 qf[2][2];  // hoisted; wave w reads only rows [32w,32w+32) == its P region
#pragma unroll
  for (int mb = 0; mb < 2; ++mb)
#pragma unroll
    for (int ks = 0; ks < 2; ++ks) {
      int row = wave * 32 + mb * 16 + ml;
      int gs = (ks * 4 + quad) ^ (row & 7);
      qf[mb][ks] = *(const short8*)(QP + row * 64 + gs * 8);
    }
  __syncthreads();  // all qf reads done before P aliases Q region

  ushort_t* Pw = QP + wave * 2048;  // per-wave P [32][64] XOR-swizzled

  // ---- hoisted LDS fragment pointers (kt-invariant; buffer1 = +4096)
  const ushort_t* kfp[4][2];
  const ushort_t* vfp[4][2];
#pragma unroll
  for (int nb = 0; nb < 4; ++nb)
#pragma unroll
    for (int ks = 0; ks < 2; ++ks) {
      int row = nb * 16 + ml;
      int gs = (ks * 4 + quad) ^ (row & 7);
      kfp[nb][ks] = Ks[0] + row * 64 + gs * 8;
      vfp[nb][ks] = Vts[0] + row * 64 + gs * 8;
    }
  // P read ptrs: row=mb*16+ml, 16B group (ks*4+quad)^(row&7)
  const ushort_t* pfp[2][2];
#pragma unroll
  for (int mb = 0; mb < 2; ++mb)
#pragma unroll
    for (int ks = 0; ks < 2; ++ks) {
      int row = mb * 16 + ml;
      int gs = ((ks * 4 + quad) ^ row) & 7;
      pfp[mb][ks] = Pw + row * 64 + gs * 8;
    }
  // P write ptrs: row=mb*16+quad*4+rg, 8B at group (ml>>1)^(row&7), sub (ml&1)*4
  ushort_t* pwp[2][4];
#pragma unroll
  for (int mb = 0; mb < 2; ++mb)
#pragma unroll
    for (int rg = 0; rg < 4; ++rg) {
      int row = mb * 16 + quad * 4 + rg;
      int g = ((ml >> 1) ^ row) & 7;
      pwp[mb][rg] = Pw + row * 64 + g * 8 + (ml & 1) * 4;
    }

  f32x4 Oacc[2][4] = {};
  float lsum[2][4] = {};

  // Per step (CUR = kt&1, compile-time): ONE barrier, full-step latency window.
#define ATTN_STEP(CUR, LAST)                                                  \
  {                                                                           \
    if (!(LAST)) {                                                            \
      load_lds16(kg, kl + ((CUR) ^ 1) * 4096); kg += 4096;                    \
      load_lds16(vg, vl + ((CUR) ^ 1) * 4096); vg += 64;                      \
    }                                                                         \
    f32x4 Sacc[2][4] = {};                                                    \
    __builtin_amdgcn_s_setprio(1);                                            \
    _Pragma("unroll") for (int nb = 0; nb < 4; ++nb)                          \
      _Pragma("unroll") for (int ks = 0; ks < 2; ++ks) {                      \
        short8 kf = *(const short8*)(kfp[nb][ks] + (CUR) * 4096);             \
        Sacc[0][nb] = MFMA16(qf[0][ks], kf, Sacc[0][nb]);                     \
        Sacc[1][nb] = MFMA16(qf[1][ks], kf, Sacc[1][nb]);                     \
      }                                                                       \
    __builtin_amdgcn_s_setprio(0);                                            \
    _Pragma("unroll") for (int mb = 0; mb < 2; ++mb) {                        \
      _Pragma("unroll") for (int rg = 0; rg < 4; ++rg) {                      \
        float p0 = fast_exp2(Sacc[mb][0][rg]);                                \
        float p1 = fast_exp2(Sacc[mb][1][rg]);                                \
        float p2 = fast_exp2(Sacc[mb][2][rg]);                                \
        float p3 = fast_exp2(Sacc[mb][3][rg]);                                \
        lsum[mb][rg] += (p0 + p1) + (p2 + p3);                                \
        uint2 w;                                                              \
        w.x = pack2(p0, p1);                                                  \
        w.y = pack2(p2, p3);                                                  \
        *(uint2*)pwp[mb][rg] = w;                                             \
      }                                                                       \
    }                                                                         \
    __builtin_amdgcn_s_setprio(1);                                            \
    _Pragma("unroll") for (int ks = 0; ks < 2; ++ks) {                        \
      short8 pf0 = *(const short8*)pfp[0][ks];                                \
      short8 pf1 = *(const short8*)pfp[1][ks];                                \
      _Pragma("unroll") for (int nb = 0; nb < 4; ++nb) {                      \
        short8 vf = *(const short8*)(vfp[nb][ks] + (CUR) * 4096);             \
        Oacc[0][nb] = MFMA16(pf0, vf, Oacc[0][nb]);                           \
        Oacc[1][nb] = MFMA16(pf1, vf, Oacc[1][nb]);                           \
      }                                                                       \
    }                                                                         \
    __builtin_amdgcn_s_setprio(0);                                            \
    __syncthreads();                                                          \
  }

#pragma unroll 1
  for (int kt2 = 0; kt2 < 8; ++kt2) {
    ATTN_STEP(0, false)
    ATTN_STEP(1, kt2 == 7)
  }
#undef ATTN_STEP

  // epilogue: reduce lsum across the 16 lanes of each quad, normalize, store
  const int b = bh >> 4, h = bh & 15;
#pragma unroll
  for (int mb = 0; mb < 2; ++mb) {
#pragma unroll
    for (int rg = 0; rg < 4; ++rg) {
      float l = lsum[mb][rg];
      l += __shfl_xor(l, 1);
      l += __shfl_xor(l, 2);
      l += __shfl_xor(l, 4);
      l += __shfl_xor(l, 8);
      float inv = 1.f / l;
      int q = q0 + wave * 32 + mb * 16 + quad * 4 + rg;
      size_t ob = ((size_t)(b * 1024 + q)) * 1024 + h * 64;
#pragma unroll
      for (int nb = 0; nb < 4; ++nb)
        Ob[ob + nb * 16 + ml] = f2bf(Oacc[mb][nb][rg] * inv);
    }
  }
}

// ---------------------------------------------------------------- proj GEMM
// A: attn bf16 [8192][1024], Bt: wproj^T bf16 [1024][1024], BK=128.
// 1D grid 512, XCD-swizzled: xcd=L&7, j=L>>3, y=xcd*8+j/8, x=j%8 -> the 8
// N-tiles sharing one A-row-block co-locate on one XCD.
__global__ __launch_bounds__(256) void k_proj_gemm(const ushort_t* __restrict__ A,
                                                   const ushort_t* __restrict__ Bt,
                                                   const float* __restrict__ bias,
                                                   float* __restrict__ out) {
  constexpr int K = 1024;
  __shared__ __align__(16) ushort_t As[128 * 128];
  __shared__ __align__(16) ushort_t Bs[128 * 128];
  const int tid = threadIdx.x, lane = tid & 63, wave = tid >> 6;
  const int quad = lane >> 4, ml = lane & 15;
  const int wm = wave & 1, wn = wave >> 1;
  const int L = blockIdx.x, xcd = L & 7, j = L >> 3;
  const int by = xcd * 8 + (j >> 3), bx = j & 7;
  const int m0 = by * 128, n0 = bx * 128;
  f32x4 acc[4][4] = {};

  for (int kt = 0; kt < K / 128; ++kt) {
    __syncthreads();
    {
      const int kk0 = kt * 128;
#pragma unroll
      for (int i = 0; i < 8; ++i) {  // 128x128 tiles: 2048 chunks of 16B each
        int cch = i * 256 + tid;
        int r = cch >> 4, s = cch & 15, gs = s ^ (r & 15);
        load_lds16(A + (size_t)(m0 + r) * K + kk0 + gs * 8, As + cch * 8);
        load_lds16(Bt + (size_t)(n0 + r) * K + kk0 + gs * 8, Bs + cch * 8);
      }
    }
    __syncthreads();
#pragma unroll
    for (int ks = 0; ks < 4; ++ks) {
      short8 af[4], bfr[4];
#pragma unroll
      for (int mb = 0; mb < 4; ++mb) {
        int row = wm * 64 + mb * 16 + ml;
        int gs = (ks * 4 + quad) ^ (row & 15);
        af[mb] = *(const short8*)(As + row * 128 + gs * 8);
      }
#pragma unroll
      for (int nb = 0; nb < 4; ++nb) {
        int row = wn * 64 + nb * 16 + ml;
        int gs = (ks * 4 + quad) ^ (row & 15);
        bfr[nb] = *(const short8*)(Bs + row * 128 + gs * 8);
      }
#pragma unroll
      for (int mb = 0; mb < 4; ++mb)
#pragma unroll
        for (int nb = 0; nb < 4; ++nb)
          acc[mb][nb] = MFMA16(af[mb], bfr[nb], acc[mb][nb]);
    }
  }
#pragma unroll
  for (int mb = 0; mb < 4; ++mb) {
#pragma unroll
    for (int rg = 0; rg < 4; ++rg) {
      const int m = m0 + wm * 64 + mb * 16 + quad * 4 + rg;
#pragma unroll
      for (int nb = 0; nb < 4; ++nb) {
        const int n = n0 + wn * 64 + nb * 16 + ml;
        out[(size_t)m * 1024 + n] = acc[mb][nb][rg] + bias[n];
      }
    }
  }
}

// ---------------------------------------------------------------- launch
extern "C" void kernel_launch(void* const* d_in, const int* in_sizes, int n_in,
                              void* d_out, int out_size, void* d_ws, size_t ws_size,
                              hipStream_t stream) {
  const float* hs = (const float*)d_in[0];
  const float* cosb = (const float*)d_in[1];
  const float* sinb = (const float*)d_in[2];
  const float* wqkv = (const float*)d_in[3];
  const float* bqkv = (const float*)d_in[4];
  const float* wproj = (const float*)d_in[5];
  const float* bproj = (const float*)d_in[6];
  float* out = (float*)d_out;

  char* ws = (char*)d_ws;
  ushort_t* hsb = (ushort_t*)(ws);
  ushort_t* wqkvT = (ushort_t*)(ws + (16u << 20));
  ushort_t* wprojT = (ushort_t*)(ws + (22u << 20));
  ushort_t* Qb = (ushort_t*)(ws + (24u << 20));
  ushort_t* Kb = (ushort_t*)(ws + (40u << 20));
  ushort_t* Vp = (ushort_t*)(ws + (56u << 20));
  ushort_t* attnb = hsb;  // hs consumed by qkv GEMM before attention writes

  k_prep<<<5120, 256, 0, stream>>>(hs, hsb, wqkv, wqkvT, wproj, wprojT);
  k_qkv_gemm_rope<<<1536, 256, 0, stream>>>(hsb, wqkvT, bqkv, cosb, sinb,
                                            Qb, Kb, Vp);
  k_attn<<<512, 512, 0, stream>>>(Qb, Kb, Vp, attnb);
  k_proj_gemm<<<512, 256, 0, stream>>>(attnb, wprojT, bproj, out);
}

// Round 7
// 243.278 us; speedup vs baseline: 1.6644x; 1.0762x over previous
//
#include <hip/hip_runtime.h>

typedef unsigned short ushort_t;
typedef __attribute__((ext_vector_type(8))) short short8;
typedef __attribute__((ext_vector_type(4))) float f32x4;

#define AS1 __attribute__((address_space(1)))
#define AS3 __attribute__((address_space(3)))

__device__ __forceinline__ ushort_t f2bf(float f) {
  unsigned int u = __builtin_bit_cast(unsigned int, f);
  u += 0x7fffu + ((u >> 16) & 1u);            // round-to-nearest-even
  return (ushort_t)(u >> 16);
}

// pack two floats to bf16x2 (round-half-up fallback; HW cvt_pk when available)
__device__ __forceinline__ unsigned int pack_bf2(float a, float b) {
  unsigned int ua = __builtin_bit_cast(unsigned int, a) + 0x8000u;
  unsigned int ub = __builtin_bit_cast(unsigned int, b) + 0x8000u;
  return (ua >> 16) | (ub & 0xffff0000u);
}

#if defined(__has_builtin)
#if __has_builtin(__builtin_amdgcn_cvt_pk_bf16_f32)
#define HAVE_CVT_PK_BF16 1
#endif
#if __has_builtin(__builtin_amdgcn_exp2f)
#define HAVE_EXP2 1
#endif
#endif

__device__ __forceinline__ unsigned int pack2(float a, float b) {
#ifdef HAVE_CVT_PK_BF16
  typedef __attribute__((ext_vector_type(2))) __bf16 bf2_t;
  bf2_t r = __builtin_amdgcn_cvt_pk_bf16_f32(a, b);
  return __builtin_bit_cast(unsigned int, r);
#else
  return pack_bf2(a, b);
#endif
}

__device__ __forceinline__ float fast_exp2(float x) {
#ifdef HAVE_EXP2
  return __builtin_amdgcn_exp2f(x);
#else
  return exp2f(x);
#endif
}

__device__ __forceinline__ void load_lds16(const ushort_t* g, ushort_t* l) {
  __builtin_amdgcn_global_load_lds((AS1 void*)g, (AS3 void*)l, 16, 0, 0);
}

#define MFMA16(a, b, c) __builtin_amdgcn_mfma_f32_16x16x32_bf16((a), (b), (c), 0, 0, 0)

// ---------------- fused prep: hs convert (blocks 0..4095) + wqkv transpose
// (4096..4863) + wproj transpose (4864..5119). One launch, runs concurrently.
__global__ __launch_bounds__(256) void k_prep(const float* __restrict__ hs,
                                              ushort_t* __restrict__ hsb,
                                              const float* __restrict__ wqkv,
                                              ushort_t* __restrict__ wqkvT,
                                              const float* __restrict__ wproj,
                                              ushort_t* __restrict__ wprojT) {
  __shared__ ushort_t t[64 * 65];
  const int bid = blockIdx.x;
  if (bid < 4096) {  // ---- convert hs fp32 -> bf16, 8 elems/thread
    int i = bid * 256 + threadIdx.x;
    const float4* s4 = (const float4*)hs;
    float4 a = s4[(size_t)i * 2], b = s4[(size_t)i * 2 + 1];
    short8 o;
    o[0] = (short)f2bf(a.x); o[1] = (short)f2bf(a.y);
    o[2] = (short)f2bf(a.z); o[3] = (short)f2bf(a.w);
    o[4] = (short)f2bf(b.x); o[5] = (short)f2bf(b.y);
    o[6] = (short)f2bf(b.z); o[7] = (short)f2bf(b.w);
    *(short8*)(hsb + (size_t)i * 8) = o;
    return;
  }
  // ---- transpose fp32 [1024][C] -> bf16 [C][1024]
  const float* src;
  ushort_t* dst;
  int C, bx, by;
  if (bid < 4864) { int idx = bid - 4096; src = wqkv; dst = wqkvT; C = 3072;
                    bx = idx % 48; by = idx / 48; }
  else            { int idx = bid - 4864; src = wproj; dst = wprojT; C = 1024;
                    bx = idx & 15; by = idx >> 4; }
  const int R = 1024;
  const int x0 = bx * 64, y0 = by * 64;
  const int c = threadIdx.x & 63, r0 = threadIdx.x >> 6;
#pragma unroll
  for (int i = 0; i < 16; ++i) {
    int r = r0 + i * 4;
    t[c * 65 + r] = f2bf(src[(size_t)(y0 + r) * C + x0 + c]);
  }
  __syncthreads();
#pragma unroll
  for (int i = 0; i < 16; ++i) {
    int rr = r0 + i * 4;
    dst[(size_t)(x0 + rr) * R + y0 + c] = t[rr * 65 + c];
  }
}

// ---------------------------------------------------------------- qkv GEMM + RoPE
// (round-1 measured-best version: 71.9 us)
// A: hs bf16 [8192][1024], Bt: wqkv^T bf16 [3072][1024]
// 256x128 tile, BK=64, 512 threads (8 waves: 4 on M x 2 on N, 64x64 each).
// 1D grid 768, XCD-swizzled: xcd=L&7, j=L>>3, y=xcd*4+j/24, x=j%24 -> the 24
// N-tiles sharing one A-row-block co-locate on one XCD (A fetched once, DMA
// staging hits local L2 instead of HBM).
// Q: RoPE'd AND pre-scaled by 0.125*log2(e) (attn computes exp2(S) directly).
// K: RoPE'd, [B*H][L][D]. V: transposed pi-space Vp[bh][d][lB + pi(lt)],
// pi(lt)=4*(lt&15)+(lt>>4) -> mb is the stride-1 axis -> packed b64 stores.
__global__ __launch_bounds__(512) void k_qkv_gemm_rope(
    const ushort_t* __restrict__ A, const ushort_t* __restrict__ Bt,
    const float* __restrict__ bias, const float* __restrict__ cosb,
    const float* __restrict__ sinb, ushort_t* __restrict__ Qb,
    ushort_t* __restrict__ Kb, ushort_t* __restrict__ Vp) {
  constexpr int K = 1024;
  __shared__ __align__(16) ushort_t As[256 * 64];
  __shared__ __align__(16) ushort_t Bs[128 * 64];
  const int tid = threadIdx.x, lane = tid & 63, wave = tid >> 6;
  const int quad = lane >> 4, ml = lane & 15;
  const int wm = wave & 3, wn = wave >> 2;  // 4 waves on M, 2 on N
  const int L = blockIdx.x, xcd = L & 7, j = L >> 3;
  const int by = xcd * 4 + j / 24, bx = j % 24;   // XCD-local A reuse
  const int m0 = by * 256, n0 = bx * 128;
  f32x4 acc[4][4] = {};

  for (int kt = 0; kt < K / 64; ++kt) {
    __syncthreads();
    {
      const int kk0 = kt * 64;
#pragma unroll
      for (int i = 0; i < 4; ++i) {  // A-tile 256x64
        int cch = i * 512 + tid;
        int r = cch >> 3, s = cch & 7, gs = s ^ (r & 7);
        load_lds16(A + (size_t)(m0 + r) * K + kk0 + gs * 8, As + cch * 8);
      }
#pragma unroll
      for (int i = 0; i < 2; ++i) {  // B-tile 128x64
        int cch = i * 512 + tid;
        int r = cch >> 3, s = cch & 7, gs = s ^ (r & 7);
        load_lds16(Bt + (size_t)(n0 + r) * K + kk0 + gs * 8, Bs + cch * 8);
      }
    }
    __syncthreads();
#pragma unroll
    for (int ks = 0; ks < 2; ++ks) {
      short8 af[4], bfr[4];
#pragma unroll
      for (int mb = 0; mb < 4; ++mb) {
        int row = wm * 64 + mb * 16 + ml;
        int gs = (ks * 4 + quad) ^ (row & 7);
        af[mb] = *(const short8*)(As + row * 64 + gs * 8);
      }
#pragma unroll
      for (int nb = 0; nb < 4; ++nb) {
        int row = wn * 64 + nb * 16 + ml;
        int gs = (ks * 4 + quad) ^ (row & 7);
        bfr[nb] = *(const short8*)(Bs + row * 64 + gs * 8);
      }
#pragma unroll
      for (int mb = 0; mb < 4; ++mb)
#pragma unroll
        for (int nb = 0; nb < 4; ++nb)
          acc[mb][nb] = MFMA16(af[mb], bfr[nb], acc[mb][nb]);
    }
  }

  // epilogue
  const int ncol0 = n0 + wn * 64;
  const int sec = ncol0 >> 10;  // 0=q 1=k 2=v
  const int h = (ncol0 & 1023) >> 6;
  if (sec < 2) {
    ushort_t* dst = (sec == 0) ? Qb : Kb;
    const float qs = (sec == 0) ? 0.18033688011112042f : 1.0f;  // log2(e)/8 into Q
#pragma unroll
    for (int mb = 0; mb < 4; ++mb) {
#pragma unroll
      for (int rg = 0; rg < 4; ++rg) {
        const int m = m0 + wm * 64 + mb * 16 + quad * 4 + rg;
        const int b = m >> 10, l = m & 1023;
        const size_t ob = ((size_t)(b * 16 + h) * 1024 + l) * 64;
#pragma unroll
        for (int nb = 0; nb < 2; ++nb) {
          const int d = nb * 16 + ml;
          float x1 = acc[mb][nb][rg] + bias[ncol0 + d];
          float x2 = acc[mb][nb + 2][rg] + bias[ncol0 + d + 32];
          float cv = cosb[(size_t)m * 64 + d] * qs;
          float sv = sinb[(size_t)m * 64 + d] * qs;
          dst[ob + d] = f2bf(x1 * cv - x2 * sv);
          dst[ob + d + 32] = f2bf(x2 * cv + x1 * sv);
        }
      }
    }
  } else {
    // V^T pi-space: addr = [bh][d][lB + 16*quad + 4*rg + mb], mb packs into b64
    const int mrow = m0 + wm * 64;
    const int b = mrow >> 10, lB = mrow & 1023;
    ushort_t* vb = Vp + ((size_t)(b * 16 + h)) * 65536 + lB;
#pragma unroll
    for (int rg = 0; rg < 4; ++rg) {
#pragma unroll
      for (int nb = 0; nb < 4; ++nb) {
        const int d = nb * 16 + ml;
        const float bs = bias[ncol0 + d];
        uint2 w;
        w.x = pack_bf2(acc[0][nb][rg] + bs, acc[1][nb][rg] + bs);
        w.y = pack_bf2(acc[2][nb][rg] + bs, acc[3][nb][rg] + bs);
        *(uint2*)(vb + (size_t)d * 1024 + 16 * quad + 4 * rg) = w;
      }
    }
  }
}

// ---------------------------------------------------------------- flash attention
// (round-2-fix version, pass-verified in rounds 3 and 6)
// Q(prescaled)/K bf16 [B*H][L][D]; Vp bf16 [B*H][D][L] (pi-space l);
// out: attn bf16 [T][H*D]. 512 THREADS (8 waves x 32 q = 256 q/block).
// K AND V double-buffered, ONE barrier per kt-step:
//   at step kt: issue K/V[kt+1] -> buf^1; QK from Kbuf[cur] (resident since
//   prev barrier); softmax -> P (wave-private LDS: wave w's Q-frag reads and
//   P region are both exactly ushorts [2048w, 2048w+2048)); PV from Vbuf[cur];
//   __syncthreads (drains vmcnt -> kt+1 resident; buf[cur] reusable).
// LDS 32K(Q/P) + 16K(K dbuf) + 16K(V dbuf) = 64KB -> 2 blocks/CU; grid 512 =
// exactly 2/CU, zero tail. K/V L2 traffic halves (4 qt-blocks per bh).
// bh = id&127: the 4 qt-blocks of one bh differ by 128 ≡ 0 mod 8 -> same XCD.
__global__ __launch_bounds__(512, 4) void k_attn(const ushort_t* __restrict__ Qb,
                                                 const ushort_t* __restrict__ Kb,
                                                 const ushort_t* __restrict__ Vp,
                                                 ushort_t* __restrict__ Ob) {
  __shared__ __align__(16) ushort_t QP[16384];     // 32KB: Q 256x64, then P 8x[32][64]
  __shared__ __align__(16) ushort_t Ks[2][4096];   // K tiles, double-buffered
  __shared__ __align__(16) ushort_t Vts[2][4096];  // V^T tiles, double-buffered
  const int tid = threadIdx.x, lane = tid & 63, wave = tid >> 6;
  const int quad = lane >> 4, ml = lane & 15;
  const int bh = blockIdx.x & 127, qt = blockIdx.x >> 7;  // 512 blocks, qt 0..3
  const int q0 = qt * 256;
  const size_t base = (size_t)bh * 65536;

#pragma unroll
  for (int i = 0; i < 4; ++i) {  // stage Q 256x64 once (32KB, 2048 chunks)
    int cch = i * 512 + tid;
    int r = cch >> 3, s = cch & 7, gs = s ^ (r & 7);
    load_lds16(Qb + base + (size_t)(q0 + r) * 64 + gs * 8, QP + cch * 8);
  }

  // ---- staging pointers: 512 threads, 512 chunks/tile -> 1 chunk per thread
  const ushort_t* kg;
  const ushort_t* vg;
  ushort_t *kl, *vl;
  {
    int cch = tid;
    int r = cch >> 3, gs = (cch & 7) ^ (r & 7);
    kg = Kb + base + (size_t)r * 64 + gs * 8;
    kl = Ks[0] + cch * 8;
    vg = Vp + base + (size_t)r * 1024 + gs * 8;
    vl = Vts[0] + cch * 8;
  }
  // prologue: K0/V0 into buf 0 (issued with Q; one drain for all)
  load_lds16(kg, kl); kg += 4096;  // next 64 key rows
  load_lds16(vg, vl); vg += 64;    // next 64 pi-cols
  __syncthreads();  // Q + K0 + V0 resident

  short8 qf[2][2];  // hoisted; wave w reads only rows [32w,32w+32) == its P region
#pragma unroll
  for (int mb = 0; mb < 2; ++mb)
#pragma unroll
    for (int ks = 0; ks < 2; ++ks) {
      int row = wave * 32 + mb * 16 + ml;
      int gs = (ks * 4 + quad) ^ (row & 7);
      qf[mb][ks] = *(const short8*)(QP + row * 64 + gs * 8);
    }
  __syncthreads();  // all qf reads done before P aliases Q region

  ushort_t* Pw = QP + wave * 2048;  // per-wave P [32][64] XOR-swizzled

  // ---- hoisted LDS fragment pointers (kt-invariant; buffer1 = +4096)
  const ushort_t* kfp[4][2];
  const ushort_t* vfp[4][2];
#pragma unroll
  for (int nb = 0; nb < 4; ++nb)
#pragma unroll
    for (int ks = 0; ks < 2; ++ks) {
      int row = nb * 16 + ml;
      int gs = (ks * 4 + quad) ^ (row & 7);
      kfp[nb][ks] = Ks[0] + row * 64 + gs * 8;
      vfp[nb][ks] = Vts[0] + row * 64 + gs * 8;
    }
  // P read ptrs: row=mb*16+ml, 16B group (ks*4+quad)^(row&7)
  const ushort_t* pfp[2][2];
#pragma unroll
  for (int mb = 0; mb < 2; ++mb)
#pragma unroll
    for (int ks = 0; ks < 2; ++ks) {
      int row = mb * 16 + ml;
      int gs = ((ks * 4 + quad) ^ row) & 7;
      pfp[mb][ks] = Pw + row * 64 + gs * 8;
    }
  // P write ptrs: row=mb*16+quad*4+rg, 8B at group (ml>>1)^(row&7), sub (ml&1)*4
  ushort_t* pwp[2][4];
#pragma unroll
  for (int mb = 0; mb < 2; ++mb)
#pragma unroll
    for (int rg = 0; rg < 4; ++rg) {
      int row = mb * 16 + quad * 4 + rg;
      int g = ((ml >> 1) ^ row) & 7;
      pwp[mb][rg] = Pw + row * 64 + g * 8 + (ml & 1) * 4;
    }

  f32x4 Oacc[2][4] = {};
  float lsum[2][4] = {};

  // Per step (CUR = kt&1, compile-time): ONE barrier, full-step latency window.
#define ATTN_STEP(CUR, LAST)                                                  \
  {                                                                           \
    if (!(LAST)) {                                                            \
      load_lds16(kg, kl + ((CUR) ^ 1) * 4096); kg += 4096;                    \
      load_lds16(vg, vl + ((CUR) ^ 1) * 4096); vg += 64;                      \
    }                                                                         \
    f32x4 Sacc[2][4] = {};                                                    \
    __builtin_amdgcn_s_setprio(1);                                            \
    _Pragma("unroll") for (int nb = 0; nb < 4; ++nb)                          \
      _Pragma("unroll") for (int ks = 0; ks < 2; ++ks) {                      \
        short8 kf = *(const short8*)(kfp[nb][ks] + (CUR) * 4096);             \
        Sacc[0][nb] = MFMA16(qf[0][ks], kf, Sacc[0][nb]);                     \
        Sacc[1][nb] = MFMA16(qf[1][ks], kf, Sacc[1][nb]);                     \
      }                                                                       \
    __builtin_amdgcn_s_setprio(0);                                            \
    _Pragma("unroll") for (int mb = 0; mb < 2; ++mb) {                        \
      _Pragma("unroll") for (int rg = 0; rg < 4; ++rg) {                      \
        float p0 = fast_exp2(Sacc[mb][0][rg]);                                \
        float p1 = fast_exp2(Sacc[mb][1][rg]);                                \
        float p2 = fast_exp2(Sacc[mb][2][rg]);                                \
        float p3 = fast_exp2(Sacc[mb][3][rg]);                                \
        lsum[mb][rg] += (p0 + p1) + (p2 + p3);                                \
        uint2 w;                                                              \
        w.x = pack2(p0, p1);                                                  \
        w.y = pack2(p2, p3);                                                  \
        *(uint2*)pwp[mb][rg] = w;                                             \
      }                                                                       \
    }                                                                         \
    __builtin_amdgcn_s_setprio(1);                                            \
    _Pragma("unroll") for (int ks = 0; ks < 2; ++ks) {                        \
      short8 pf0 = *(const short8*)pfp[0][ks];                                \
      short8 pf1 = *(const short8*)pfp[1][ks];                                \
      _Pragma("unroll") for (int nb = 0; nb < 4; ++nb) {                      \
        short8 vf = *(const short8*)(vfp[nb][ks] + (CUR) * 4096);             \
        Oacc[0][nb] = MFMA16(pf0, vf, Oacc[0][nb]);                           \
        Oacc[1][nb] = MFMA16(pf1, vf, Oacc[1][nb]);                           \
      }                                                                       \
    }                                                                         \
    __builtin_amdgcn_s_setprio(0);                                            \
    __syncthreads();                                                          \
  }

#pragma unroll 1
  for (int kt2 = 0; kt2 < 8; ++kt2) {
    ATTN_STEP(0, false)
    ATTN_STEP(1, kt2 == 7)
  }
#undef ATTN_STEP

  // epilogue: reduce lsum across the 16 lanes of each quad, normalize, store
  const int b = bh >> 4, h = bh & 15;
#pragma unroll
  for (int mb = 0; mb < 2; ++mb) {
#pragma unroll
    for (int rg = 0; rg < 4; ++rg) {
      float l = lsum[mb][rg];
      l += __shfl_xor(l, 1);
      l += __shfl_xor(l, 2);
      l += __shfl_xor(l, 4);
      l += __shfl_xor(l, 8);
      float inv = 1.f / l;
      int q = q0 + wave * 32 + mb * 16 + quad * 4 + rg;
      size_t ob = ((size_t)(b * 1024 + q)) * 1024 + h * 64;
#pragma unroll
      for (int nb = 0; nb < 4; ++nb)
        Ob[ob + nb * 16 + ml] = f2bf(Oacc[mb][nb][rg] * inv);
    }
  }
}

// ---------------------------------------------------------------- proj GEMM
// A: attn bf16 [8192][1024], Bt: wproj^T bf16 [1024][1024], BK=128.
// 1D grid 512, XCD-swizzled: xcd=L&7, j=L>>3, y=xcd*8+j/8, x=j%8 -> the 8
// N-tiles sharing one A-row-block co-locate on one XCD.
__global__ __launch_bounds__(256) void k_proj_gemm(const ushort_t* __restrict__ A,
                                                   const ushort_t* __restrict__ Bt,
                                                   const float* __restrict__ bias,
                                                   float* __restrict__ out) {
  constexpr int K = 1024;
  __shared__ __align__(16) ushort_t As[128 * 128];
  __shared__ __align__(16) ushort_t Bs[128 * 128];
  const int tid = threadIdx.x, lane = tid & 63, wave = tid >> 6;
  const int quad = lane >> 4, ml = lane & 15;
  const int wm = wave & 1, wn = wave >> 1;
  const int L = blockIdx.x, xcd = L & 7, j = L >> 3;
  const int by = xcd * 8 + (j >> 3), bx = j & 7;
  const int m0 = by * 128, n0 = bx * 128;
  f32x4 acc[4][4] = {};

  for (int kt = 0; kt < K / 128; ++kt) {
    __syncthreads();
    {
      const int kk0 = kt * 128;
#pragma unroll
      for (int i = 0; i < 8; ++i) {  // 128x128 tiles: 2048 chunks of 16B each
        int cch = i * 256 + tid;
        int r = cch >> 4, s = cch & 15, gs = s ^ (r & 15);
        load_lds16(A + (size_t)(m0 + r) * K + kk0 + gs * 8, As + cch * 8);
        load_lds16(Bt + (size_t)(n0 + r) * K + kk0 + gs * 8, Bs + cch * 8);
      }
    }
    __syncthreads();
#pragma unroll
    for (int ks = 0; ks < 4; ++ks) {
      short8 af[4], bfr[4];
#pragma unroll
      for (int mb = 0; mb < 4; ++mb) {
        int row = wm * 64 + mb * 16 + ml;
        int gs = (ks * 4 + quad) ^ (row & 15);
        af[mb] = *(const short8*)(As + row * 128 + gs * 8);
      }
#pragma unroll
      for (int nb = 0; nb < 4; ++nb) {
        int row = wn * 64 + nb * 16 + ml;
        int gs = (ks * 4 + quad) ^ (row & 15);
        bfr[nb] = *(const short8*)(Bs + row * 128 + gs * 8);
      }
#pragma unroll
      for (int mb = 0; mb < 4; ++mb)
#pragma unroll
        for (int nb = 0; nb < 4; ++nb)
          acc[mb][nb] = MFMA16(af[mb], bfr[nb], acc[mb][nb]);
    }
  }
#pragma unroll
  for (int mb = 0; mb < 4; ++mb) {
#pragma unroll
    for (int rg = 0; rg < 4; ++rg) {
      const int m = m0 + wm * 64 + mb * 16 + quad * 4 + rg;
#pragma unroll
      for (int nb = 0; nb < 4; ++nb) {
        const int n = n0 + wn * 64 + nb * 16 + ml;
        out[(size_t)m * 1024 + n] = acc[mb][nb][rg] + bias[n];
      }
    }
  }
}

// ---------------------------------------------------------------- launch
extern "C" void kernel_launch(void* const* d_in, const int* in_sizes, int n_in,
                              void* d_out, int out_size, void* d_ws, size_t ws_size,
                              hipStream_t stream) {
  const float* hs = (const float*)d_in[0];
  const float* cosb = (const float*)d_in[1];
  const float* sinb = (const float*)d_in[2];
  const float* wqkv = (const float*)d_in[3];
  const float* bqkv = (const float*)d_in[4];
  const float* wproj = (const float*)d_in[5];
  const float* bproj = (const float*)d_in[6];
  float* out = (float*)d_out;

  char* ws = (char*)d_ws;
  ushort_t* hsb = (ushort_t*)(ws);
  ushort_t* wqkvT = (ushort_t*)(ws + (16u << 20));
  ushort_t* wprojT = (ushort_t*)(ws + (22u << 20));
  ushort_t* Qb = (ushort_t*)(ws + (24u << 20));
  ushort_t* Kb = (ushort_t*)(ws + (40u << 20));
  ushort_t* Vp = (ushort_t*)(ws + (56u << 20));
  ushort_t* attnb = hsb;  // hs consumed by qkv GEMM before attention writes

  k_prep<<<5120, 256, 0, stream>>>(hs, hsb, wqkv, wqkvT, wproj, wprojT);
  k_qkv_gemm_rope<<<768, 512, 0, stream>>>(hsb, wqkvT, bqkv, cosb, sinb,
                                           Qb, Kb, Vp);
  k_attn<<<512, 512, 0, stream>>>(Qb, Kb, Vp, attnb);
  k_proj_gemm<<<512, 256, 0, stream>>>(attnb, wprojT, bproj, out);
}